// Round 4
// baseline (193.504 us; speedup 1.0000x reference)
//
#include <hip/hip_runtime.h>
#include <float.h>

#define NSRC 100000
#define NDST 10000
#define NEDGE 320000
#define FIN 128
#define HID 256
#define NCLS 3
#define NEG_SLOPE 0.2f

// ---------- prep (129 blocks x 64 lanes):
//   blocks 0..127: k = blockIdx -> wa_src[k], wa_dst[k], wfc[c][k] = (W@Wc)[k,c]
//   block 128: bf[c] = bias @ Wc[:,c] + bc[c]
__global__ void prep_kernel(const float* __restrict__ W, const float* __restrict__ att_src,
                            const float* __restrict__ att_dst, const float* __restrict__ bias,
                            const float* __restrict__ Wc, const float* __restrict__ bc,
                            float* __restrict__ wa_src, float* __restrict__ wa_dst,
                            float* __restrict__ wfc, float* __restrict__ bf) {
  int l = threadIdx.x;  // 0..63
  if (blockIdx.x < FIN) {
    int k = blockIdx.x;
    float4 w = ((const float4*)(W + (size_t)k * HID))[l];  // 64 lanes x 4 = 256 = HID
    int h0 = 4 * l;
    float s1 = w.x * att_src[h0] + w.y * att_src[h0 + 1] + w.z * att_src[h0 + 2] + w.w * att_src[h0 + 3];
    float s2 = w.x * att_dst[h0] + w.y * att_dst[h0 + 1] + w.z * att_dst[h0 + 2] + w.w * att_dst[h0 + 3];
    float f0 = w.x * Wc[h0 * NCLS] + w.y * Wc[(h0 + 1) * NCLS] + w.z * Wc[(h0 + 2) * NCLS] + w.w * Wc[(h0 + 3) * NCLS];
    float f1 = w.x * Wc[h0 * NCLS + 1] + w.y * Wc[(h0 + 1) * NCLS + 1] + w.z * Wc[(h0 + 2) * NCLS + 1] + w.w * Wc[(h0 + 3) * NCLS + 1];
    float f2 = w.x * Wc[h0 * NCLS + 2] + w.y * Wc[(h0 + 1) * NCLS + 2] + w.z * Wc[(h0 + 2) * NCLS + 2] + w.w * Wc[(h0 + 3) * NCLS + 2];
#pragma unroll
    for (int off = 32; off; off >>= 1) {
      s1 += __shfl_down(s1, off);
      s2 += __shfl_down(s2, off);
      f0 += __shfl_down(f0, off);
      f1 += __shfl_down(f1, off);
      f2 += __shfl_down(f2, off);
    }
    if (l == 0) {
      wa_src[k] = s1;
      wa_dst[k] = s2;
      wfc[0 * FIN + k] = f0;
      wfc[1 * FIN + k] = f1;
      wfc[2 * FIN + k] = f2;
    }
  } else {
    float b0 = 0.f, b1 = 0.f, b2 = 0.f;
#pragma unroll
    for (int j = 0; j < 4; ++j) {
      int h = l + 64 * j;
      float bi = bias[h];
      b0 += bi * Wc[h * NCLS + 0];
      b1 += bi * Wc[h * NCLS + 1];
      b2 += bi * Wc[h * NCLS + 2];
    }
#pragma unroll
    for (int off = 32; off; off >>= 1) {
      b0 += __shfl_down(b0, off);
      b1 += __shfl_down(b1, off);
      b2 += __shfl_down(b2, off);
    }
    if (l == 0) {
      bf[0] = b0 + bc[0];
      bf[1] = b1 + bc[1];
      bf[2] = b2 + bc[2];
    }
  }
}

// ---------- fused matvec over src+dst rows (half-wave per row, float4 loads)
//   row < NSRC:  a_src[row] = x.wa_src ; q4[row] = (x.Wf0, x.Wf1, x.Wf2, 1.0)
//   else (dst):  a_dst[rd]  = x.wa_dst ; acc4[rd] = 0  (zeroed for edge pass)
__global__ void matvec_fused_kernel(const float* __restrict__ x_src, const float* __restrict__ x_dst,
                                    const float* __restrict__ wa_src, const float* __restrict__ wa_dst,
                                    const float* __restrict__ wfc, float* __restrict__ a_src,
                                    float* __restrict__ a_dst, float4* __restrict__ q4,
                                    float4* __restrict__ acc4) {
  int gid = blockIdx.x * blockDim.x + threadIdx.x;
  int row = gid >> 5;
  int l = threadIdx.x & 31;
  if (row < NSRC) {
    float4 v = ((const float4*)(x_src + (size_t)row * FIN))[l];
    float4 w = ((const float4*)wa_src)[l];
    float4 c0 = ((const float4*)(wfc + 0 * FIN))[l];
    float4 c1 = ((const float4*)(wfc + 1 * FIN))[l];
    float4 c2 = ((const float4*)(wfc + 2 * FIN))[l];
    float p0 = v.x * w.x + v.y * w.y + v.z * w.z + v.w * w.w;
    float p1 = v.x * c0.x + v.y * c0.y + v.z * c0.z + v.w * c0.w;
    float p2 = v.x * c1.x + v.y * c1.y + v.z * c1.z + v.w * c1.w;
    float p3 = v.x * c2.x + v.y * c2.y + v.z * c2.z + v.w * c2.w;
#pragma unroll
    for (int off = 16; off; off >>= 1) {
      p0 += __shfl_down(p0, off);
      p1 += __shfl_down(p1, off);
      p2 += __shfl_down(p2, off);
      p3 += __shfl_down(p3, off);
    }
    if (l == 0) {
      a_src[row] = p0;
      q4[row] = make_float4(p1, p2, p3, 1.0f);
    }
  } else {
    int rd = row - NSRC;
    if (rd >= NDST) return;
    float4 v = ((const float4*)(x_dst + (size_t)rd * FIN))[l];
    float4 w = ((const float4*)wa_dst)[l];
    float p = v.x * w.x + v.y * w.y + v.z * w.z + v.w * w.w;
#pragma unroll
    for (int off = 16; off; off >>= 1) p += __shfl_down(p, off);
    if (l == 0) {
      a_dst[rd] = p;
      acc4[rd] = make_float4(0.f, 0.f, 0.f, 0.f);
    }
  }
}

// ---------- edge pass: w = exp(leaky_relu(a_dst[d]+a_src[s])); atomic accumulate w * q4[s]
//   (q4.w == 1, so acc4[d].w accumulates the softmax denominator)
__global__ void edge_kernel(const int* __restrict__ edge_src, const int* __restrict__ edge_dst,
                            const float* __restrict__ a_src, const float* __restrict__ a_dst,
                            const float4* __restrict__ q4, float* __restrict__ acc) {
  int e = blockIdx.x * blockDim.x + threadIdx.x;
  if (e >= NEDGE) return;
  int s = edge_src[e], d = edge_dst[e];
  float z = a_dst[d] + a_src[s];
  float logit = (z >= 0.f) ? z : NEG_SLOPE * z;
  float w = __expf(logit);  // no max-subtraction: |logit| <= ~15 for this data scale
  float4 qv = q4[s];
  float* base = acc + (size_t)d * 4;
  atomicAdd(base + 0, w * qv.x);
  atomicAdd(base + 1, w * qv.y);
  atomicAdd(base + 2, w * qv.z);
  atomicAdd(base + 3, w);  // qv.w == 1
}

// ---------- finalize: scores = acc/denom + bf -> log_softmax ----------
__global__ void finalize_kernel(const float4* __restrict__ acc4, const float* __restrict__ bf,
                                float* __restrict__ out) {
  int d = blockIdx.x * blockDim.x + threadIdx.x;
  if (d >= NDST) return;
  float4 a = acc4[d];
  float inv = 1.f / (a.w + 1e-16f);
  float s0 = a.x * inv + bf[0];
  float s1 = a.y * inv + bf[1];
  float s2 = a.z * inv + bf[2];
  float mx = fmaxf(s0, fmaxf(s1, s2));
  float l = logf(__expf(s0 - mx) + __expf(s1 - mx) + __expf(s2 - mx));
  out[d * NCLS + 0] = s0 - mx - l;
  out[d * NCLS + 1] = s1 - mx - l;
  out[d * NCLS + 2] = s2 - mx - l;
}

extern "C" void kernel_launch(void* const* d_in, const int* in_sizes, int n_in,
                              void* d_out, int out_size, void* d_ws, size_t ws_size,
                              hipStream_t stream) {
  const float* x_src    = (const float*)d_in[0];
  const float* x_dst    = (const float*)d_in[1];
  const int*   edge_src = (const int*)d_in[2];
  const int*   edge_dst = (const int*)d_in[3];
  const float* W        = (const float*)d_in[4];
  const float* att_src  = (const float*)d_in[5];
  const float* att_dst  = (const float*)d_in[6];
  const float* bias     = (const float*)d_in[7];
  const float* Wc       = (const float*)d_in[8];
  const float* bc       = (const float*)d_in[9];
  float* out = (float*)d_out;

  // ---- workspace carve (256B aligned chunks) ----
  char* p = (char*)d_ws;
  auto carve = [&](size_t bytes) {
    void* r = (void*)p;
    p += (bytes + 255) & ~(size_t)255;
    return r;
  };
  float*  wa_src = (float*)carve(FIN * 4);
  float*  wa_dst = (float*)carve(FIN * 4);
  float*  wfc    = (float*)carve(NCLS * FIN * 4);
  float*  bf     = (float*)carve(NCLS * 4);
  float*  a_src  = (float*)carve((size_t)NSRC * 4);
  float*  a_dst  = (float*)carve((size_t)NDST * 4);
  float4* q4     = (float4*)carve((size_t)NSRC * 16);
  float4* acc4   = (float4*)carve((size_t)NDST * 16);

  prep_kernel<<<FIN + 1, 64, 0, stream>>>(W, att_src, att_dst, bias, Wc, bc,
                                          wa_src, wa_dst, wfc, bf);
  {
    int rows = NSRC + NDST;
    int blocks = (rows * 32 + 255) / 256;
    matvec_fused_kernel<<<blocks, 256, 0, stream>>>(x_src, x_dst, wa_src, wa_dst, wfc,
                                                    a_src, a_dst, q4, acc4);
  }
  edge_kernel<<<(NEDGE + 255) / 256, 256, 0, stream>>>(edge_src, edge_dst, a_src, a_dst,
                                                       q4, (float*)acc4);
  finalize_kernel<<<(NDST + 255) / 256, 256, 0, stream>>>(acc4, bf, out);
}

// Round 5
// 191.898 us; speedup vs baseline: 1.0084x; 1.0084x over previous
//
#include <hip/hip_runtime.h>
#include <float.h>

#define NSRC 100000
#define NDST 10000
#define NEDGE 320000
#define FIN 128
#define HID 256
#define NCLS 3
#define NEG_SLOPE 0.2f

// Native fp32 atomic add (global_atomic_add_f32) — avoids HIP's CAS-loop fallback,
// which was the 82 µs pathology in round 4 (contended CAS retries, VALUBusy 0.2%).
__device__ __forceinline__ void atomic_fadd_native(float* p, float v) {
#if defined(__HIP_DEVICE_COMPILE__)
  unsafeAtomicAdd(p, v);
#else
  atomicAdd(p, v);
#endif
}

// ---------- prep (129 blocks x 64 lanes):
//   blocks 0..127: k = blockIdx -> wa_src[k], wa_dst[k], wfc[c][k] = (W@Wc)[k,c]
//   block 128: bf[c] = bias @ Wc[:,c] + bc[c]
__global__ void prep_kernel(const float* __restrict__ W, const float* __restrict__ att_src,
                            const float* __restrict__ att_dst, const float* __restrict__ bias,
                            const float* __restrict__ Wc, const float* __restrict__ bc,
                            float* __restrict__ wa_src, float* __restrict__ wa_dst,
                            float* __restrict__ wfc, float* __restrict__ bf) {
  int l = threadIdx.x;  // 0..63
  if (blockIdx.x < FIN) {
    int k = blockIdx.x;
    float4 w = ((const float4*)(W + (size_t)k * HID))[l];  // 64 lanes x 4 = 256 = HID
    int h0 = 4 * l;
    float s1 = w.x * att_src[h0] + w.y * att_src[h0 + 1] + w.z * att_src[h0 + 2] + w.w * att_src[h0 + 3];
    float s2 = w.x * att_dst[h0] + w.y * att_dst[h0 + 1] + w.z * att_dst[h0 + 2] + w.w * att_dst[h0 + 3];
    float f0 = w.x * Wc[h0 * NCLS] + w.y * Wc[(h0 + 1) * NCLS] + w.z * Wc[(h0 + 2) * NCLS] + w.w * Wc[(h0 + 3) * NCLS];
    float f1 = w.x * Wc[h0 * NCLS + 1] + w.y * Wc[(h0 + 1) * NCLS + 1] + w.z * Wc[(h0 + 2) * NCLS + 1] + w.w * Wc[(h0 + 3) * NCLS + 1];
    float f2 = w.x * Wc[h0 * NCLS + 2] + w.y * Wc[(h0 + 1) * NCLS + 2] + w.z * Wc[(h0 + 2) * NCLS + 2] + w.w * Wc[(h0 + 3) * NCLS + 2];
#pragma unroll
    for (int off = 32; off; off >>= 1) {
      s1 += __shfl_down(s1, off);
      s2 += __shfl_down(s2, off);
      f0 += __shfl_down(f0, off);
      f1 += __shfl_down(f1, off);
      f2 += __shfl_down(f2, off);
    }
    if (l == 0) {
      wa_src[k] = s1;
      wa_dst[k] = s2;
      wfc[0 * FIN + k] = f0;
      wfc[1 * FIN + k] = f1;
      wfc[2 * FIN + k] = f2;
    }
  } else {
    float b0 = 0.f, b1 = 0.f, b2 = 0.f;
#pragma unroll
    for (int j = 0; j < 4; ++j) {
      int h = l + 64 * j;
      float bi = bias[h];
      b0 += bi * Wc[h * NCLS + 0];
      b1 += bi * Wc[h * NCLS + 1];
      b2 += bi * Wc[h * NCLS + 2];
    }
#pragma unroll
    for (int off = 32; off; off >>= 1) {
      b0 += __shfl_down(b0, off);
      b1 += __shfl_down(b1, off);
      b2 += __shfl_down(b2, off);
    }
    if (l == 0) {
      bf[0] = b0 + bc[0];
      bf[1] = b1 + bc[1];
      bf[2] = b2 + bc[2];
    }
  }
}

// ---------- fused matvec over src+dst rows (half-wave per row, float4 loads)
//   row < NSRC:  a_src[row] = x.wa_src ; q4[row] = (x.Wf0, x.Wf1, x.Wf2, 1.0)
//   else (dst):  a_dst[rd]  = x.wa_dst ; acc4[rd] = 0  (zeroed for edge pass)
__global__ void matvec_fused_kernel(const float* __restrict__ x_src, const float* __restrict__ x_dst,
                                    const float* __restrict__ wa_src, const float* __restrict__ wa_dst,
                                    const float* __restrict__ wfc, float* __restrict__ a_src,
                                    float* __restrict__ a_dst, float4* __restrict__ q4,
                                    float4* __restrict__ acc4) {
  int gid = blockIdx.x * blockDim.x + threadIdx.x;
  int row = gid >> 5;
  int l = threadIdx.x & 31;
  if (row < NSRC) {
    float4 v = ((const float4*)(x_src + (size_t)row * FIN))[l];
    float4 w = ((const float4*)wa_src)[l];
    float4 c0 = ((const float4*)(wfc + 0 * FIN))[l];
    float4 c1 = ((const float4*)(wfc + 1 * FIN))[l];
    float4 c2 = ((const float4*)(wfc + 2 * FIN))[l];
    float p0 = v.x * w.x + v.y * w.y + v.z * w.z + v.w * w.w;
    float p1 = v.x * c0.x + v.y * c0.y + v.z * c0.z + v.w * c0.w;
    float p2 = v.x * c1.x + v.y * c1.y + v.z * c1.z + v.w * c1.w;
    float p3 = v.x * c2.x + v.y * c2.y + v.z * c2.z + v.w * c2.w;
#pragma unroll
    for (int off = 16; off; off >>= 1) {
      p0 += __shfl_down(p0, off);
      p1 += __shfl_down(p1, off);
      p2 += __shfl_down(p2, off);
      p3 += __shfl_down(p3, off);
    }
    if (l == 0) {
      a_src[row] = p0;
      q4[row] = make_float4(p1, p2, p3, 1.0f);
    }
  } else {
    int rd = row - NSRC;
    if (rd >= NDST) return;
    float4 v = ((const float4*)(x_dst + (size_t)rd * FIN))[l];
    float4 w = ((const float4*)wa_dst)[l];
    float p = v.x * w.x + v.y * w.y + v.z * w.z + v.w * w.w;
#pragma unroll
    for (int off = 16; off; off >>= 1) p += __shfl_down(p, off);
    if (l == 0) {
      a_dst[rd] = p;
      acc4[rd] = make_float4(0.f, 0.f, 0.f, 0.f);
    }
  }
}

// ---------- edge pass: w = exp(leaky_relu(a_dst[d]+a_src[s])); native-atomic accumulate w * q4[s]
//   (q4.w == 1, so acc4[d].w accumulates the softmax denominator)
__global__ void edge_kernel(const int* __restrict__ edge_src, const int* __restrict__ edge_dst,
                            const float* __restrict__ a_src, const float* __restrict__ a_dst,
                            const float4* __restrict__ q4, float* __restrict__ acc) {
  int e = blockIdx.x * blockDim.x + threadIdx.x;
  if (e >= NEDGE) return;
  int s = edge_src[e], d = edge_dst[e];
  float z = a_dst[d] + a_src[s];
  float logit = (z >= 0.f) ? z : NEG_SLOPE * z;
  float w = __expf(logit);  // no max-subtraction: |logit| <= ~15 for this data scale
  float4 qv = q4[s];
  float* base = acc + (size_t)d * 4;
  atomic_fadd_native(base + 0, w * qv.x);
  atomic_fadd_native(base + 1, w * qv.y);
  atomic_fadd_native(base + 2, w * qv.z);
  atomic_fadd_native(base + 3, w);  // qv.w == 1
}

// ---------- finalize: scores = acc/denom + bf -> log_softmax ----------
__global__ void finalize_kernel(const float4* __restrict__ acc4, const float* __restrict__ bf,
                                float* __restrict__ out) {
  int d = blockIdx.x * blockDim.x + threadIdx.x;
  if (d >= NDST) return;
  float4 a = acc4[d];
  float inv = 1.f / (a.w + 1e-16f);
  float s0 = a.x * inv + bf[0];
  float s1 = a.y * inv + bf[1];
  float s2 = a.z * inv + bf[2];
  float mx = fmaxf(s0, fmaxf(s1, s2));
  float l = logf(__expf(s0 - mx) + __expf(s1 - mx) + __expf(s2 - mx));
  out[d * NCLS + 0] = s0 - mx - l;
  out[d * NCLS + 1] = s1 - mx - l;
  out[d * NCLS + 2] = s2 - mx - l;
}

extern "C" void kernel_launch(void* const* d_in, const int* in_sizes, int n_in,
                              void* d_out, int out_size, void* d_ws, size_t ws_size,
                              hipStream_t stream) {
  const float* x_src    = (const float*)d_in[0];
  const float* x_dst    = (const float*)d_in[1];
  const int*   edge_src = (const int*)d_in[2];
  const int*   edge_dst = (const int*)d_in[3];
  const float* W        = (const float*)d_in[4];
  const float* att_src  = (const float*)d_in[5];
  const float* att_dst  = (const float*)d_in[6];
  const float* bias     = (const float*)d_in[7];
  const float* Wc       = (const float*)d_in[8];
  const float* bc       = (const float*)d_in[9];
  float* out = (float*)d_out;

  // ---- workspace carve (256B aligned chunks) ----
  char* p = (char*)d_ws;
  auto carve = [&](size_t bytes) {
    void* r = (void*)p;
    p += (bytes + 255) & ~(size_t)255;
    return r;
  };
  float*  wa_src = (float*)carve(FIN * 4);
  float*  wa_dst = (float*)carve(FIN * 4);
  float*  wfc    = (float*)carve(NCLS * FIN * 4);
  float*  bf     = (float*)carve(NCLS * 4);
  float*  a_src  = (float*)carve((size_t)NSRC * 4);
  float*  a_dst  = (float*)carve((size_t)NDST * 4);
  float4* q4     = (float4*)carve((size_t)NSRC * 16);
  float4* acc4   = (float4*)carve((size_t)NDST * 16);

  prep_kernel<<<FIN + 1, 64, 0, stream>>>(W, att_src, att_dst, bias, Wc, bc,
                                          wa_src, wa_dst, wfc, bf);
  {
    int rows = NSRC + NDST;
    int blocks = (rows * 32 + 255) / 256;
    matvec_fused_kernel<<<blocks, 256, 0, stream>>>(x_src, x_dst, wa_src, wa_dst, wfc,
                                                    a_src, a_dst, q4, acc4);
  }
  edge_kernel<<<(NEDGE + 255) / 256, 256, 0, stream>>>(edge_src, edge_dst, a_src, a_dst,
                                                       q4, (float*)acc4);
  finalize_kernel<<<(NDST + 255) / 256, 256, 0, stream>>>(acc4, bf, out);
}

// Round 6
// 129.589 us; speedup vs baseline: 1.4932x; 1.4808x over previous
//
#include <hip/hip_runtime.h>
#include <float.h>

#define NSRC 100000
#define NDST 10000
#define NEDGE 320000
#define FIN 128
#define HID 256
#define NCLS 3
#define NEG_SLOPE 0.2f

#define RANGES 4                 // dst ranges (2500 dsts -> 40 KB LDS table each)
#define REPL 64                  // edge slices (replicas per range)
#define DPB (NDST / RANGES)      // 2500 dsts per range
#define EPB (NEDGE / REPL)       // 5000 edges per slice
#define TPB 512                  // 8 waves per block

// ---------- prep (129 blocks x 64 lanes):
//   blocks 0..127: k = blockIdx -> wa_src[k], wa_dst[k], wfc[c][k] = (W@Wc)[k,c]
//   block 128: bf[c] = bias @ Wc[:,c] + bc[c]
__global__ void prep_kernel(const float* __restrict__ W, const float* __restrict__ att_src,
                            const float* __restrict__ att_dst, const float* __restrict__ bias,
                            const float* __restrict__ Wc, const float* __restrict__ bc,
                            float* __restrict__ wa_src, float* __restrict__ wa_dst,
                            float* __restrict__ wfc, float* __restrict__ bf) {
  int l = threadIdx.x;  // 0..63
  if (blockIdx.x < FIN) {
    int k = blockIdx.x;
    float4 w = ((const float4*)(W + (size_t)k * HID))[l];  // 64 lanes x 4 = 256 = HID
    int h0 = 4 * l;
    float s1 = w.x * att_src[h0] + w.y * att_src[h0 + 1] + w.z * att_src[h0 + 2] + w.w * att_src[h0 + 3];
    float s2 = w.x * att_dst[h0] + w.y * att_dst[h0 + 1] + w.z * att_dst[h0 + 2] + w.w * att_dst[h0 + 3];
    float f0 = w.x * Wc[h0 * NCLS] + w.y * Wc[(h0 + 1) * NCLS] + w.z * Wc[(h0 + 2) * NCLS] + w.w * Wc[(h0 + 3) * NCLS];
    float f1 = w.x * Wc[h0 * NCLS + 1] + w.y * Wc[(h0 + 1) * NCLS + 1] + w.z * Wc[(h0 + 2) * NCLS + 1] + w.w * Wc[(h0 + 3) * NCLS + 1];
    float f2 = w.x * Wc[h0 * NCLS + 2] + w.y * Wc[(h0 + 1) * NCLS + 2] + w.z * Wc[(h0 + 2) * NCLS + 2] + w.w * Wc[(h0 + 3) * NCLS + 2];
#pragma unroll
    for (int off = 32; off; off >>= 1) {
      s1 += __shfl_down(s1, off);
      s2 += __shfl_down(s2, off);
      f0 += __shfl_down(f0, off);
      f1 += __shfl_down(f1, off);
      f2 += __shfl_down(f2, off);
    }
    if (l == 0) {
      wa_src[k] = s1;
      wa_dst[k] = s2;
      wfc[0 * FIN + k] = f0;
      wfc[1 * FIN + k] = f1;
      wfc[2 * FIN + k] = f2;
    }
  } else {
    float b0 = 0.f, b1 = 0.f, b2 = 0.f;
#pragma unroll
    for (int j = 0; j < 4; ++j) {
      int h = l + 64 * j;
      float bi = bias[h];
      b0 += bi * Wc[h * NCLS + 0];
      b1 += bi * Wc[h * NCLS + 1];
      b2 += bi * Wc[h * NCLS + 2];
    }
#pragma unroll
    for (int off = 32; off; off >>= 1) {
      b0 += __shfl_down(b0, off);
      b1 += __shfl_down(b1, off);
      b2 += __shfl_down(b2, off);
    }
    if (l == 0) {
      bf[0] = b0 + bc[0];
      bf[1] = b1 + bc[1];
      bf[2] = b2 + bc[2];
    }
  }
}

// ---------- fused matvec over src+dst rows (half-wave per row, float4 loads)
//   row < NSRC:  a_src[row] = x.wa_src ; q4[row] = (x.Wf0, x.Wf1, x.Wf2, 1.0)
//   else (dst):  a_dst[rd]  = x.wa_dst
__global__ void matvec_fused_kernel(const float* __restrict__ x_src, const float* __restrict__ x_dst,
                                    const float* __restrict__ wa_src, const float* __restrict__ wa_dst,
                                    const float* __restrict__ wfc, float* __restrict__ a_src,
                                    float* __restrict__ a_dst, float4* __restrict__ q4) {
  int gid = blockIdx.x * blockDim.x + threadIdx.x;
  int row = gid >> 5;
  int l = threadIdx.x & 31;
  if (row < NSRC) {
    float4 v = ((const float4*)(x_src + (size_t)row * FIN))[l];
    float4 w = ((const float4*)wa_src)[l];
    float4 c0 = ((const float4*)(wfc + 0 * FIN))[l];
    float4 c1 = ((const float4*)(wfc + 1 * FIN))[l];
    float4 c2 = ((const float4*)(wfc + 2 * FIN))[l];
    float p0 = v.x * w.x + v.y * w.y + v.z * w.z + v.w * w.w;
    float p1 = v.x * c0.x + v.y * c0.y + v.z * c0.z + v.w * c0.w;
    float p2 = v.x * c1.x + v.y * c1.y + v.z * c1.z + v.w * c1.w;
    float p3 = v.x * c2.x + v.y * c2.y + v.z * c2.z + v.w * c2.w;
#pragma unroll
    for (int off = 16; off; off >>= 1) {
      p0 += __shfl_down(p0, off);
      p1 += __shfl_down(p1, off);
      p2 += __shfl_down(p2, off);
      p3 += __shfl_down(p3, off);
    }
    if (l == 0) {
      a_src[row] = p0;
      q4[row] = make_float4(p1, p2, p3, 1.0f);
    }
  } else {
    int rd = row - NSRC;
    if (rd >= NDST) return;
    float4 v = ((const float4*)(x_dst + (size_t)rd * FIN))[l];
    float4 w = ((const float4*)wa_dst)[l];
    float p = v.x * w.x + v.y * w.y + v.z * w.z + v.w * w.w;
#pragma unroll
    for (int off = 16; off; off >>= 1) p += __shfl_down(p, off);
    if (l == 0) a_dst[rd] = p;
  }
}

// ---------- edge pass, NO global atomics:
//   block (c = blockIdx.x replica, r = blockIdx.y range) scans edge slice c,
//   keeps edges with dst in range r, accumulates (w*q0,w*q1,w*q2,w) into a
//   private 40 KB LDS table via LDS atomics, then dumps to partial[r][c][.].
__global__ __launch_bounds__(TPB) void edge_lds_kernel(
    const int* __restrict__ edge_src, const int* __restrict__ edge_dst,
    const float* __restrict__ a_src, const float* __restrict__ a_dst,
    const float4* __restrict__ q4, float* __restrict__ partial) {
  __shared__ float lacc[DPB * 4];  // 40 KB
  int c = blockIdx.x;   // 0..REPL-1
  int r = blockIdx.y;   // 0..RANGES-1
  int tid = threadIdx.x;
  for (int i = tid; i < DPB * 4; i += TPB) lacc[i] = 0.f;
  __syncthreads();

  int d0 = r * DPB;
  int ebase = c * EPB;
  for (int i = tid; i < EPB; i += TPB) {
    int e = ebase + i;
    int d = edge_dst[e];
    unsigned dr = (unsigned)(d - d0);
    if (dr < (unsigned)DPB) {
      int s = edge_src[e];
      float z = a_dst[d] + a_src[s];
      float logit = (z >= 0.f) ? z : NEG_SLOPE * z;
      float w = __expf(logit);  // no max-subtraction: |logit| small for this data scale
      float4 qv = q4[s];
      float* b = lacc + dr * 4;
      atomicAdd(b + 0, w * qv.x);
      atomicAdd(b + 1, w * qv.y);
      atomicAdd(b + 2, w * qv.z);
      atomicAdd(b + 3, w);  // qv.w == 1
    }
  }
  __syncthreads();

  float* dst = partial + ((size_t)r * REPL + c) * (DPB * 4);
  for (int i = tid; i < DPB * 4; i += TPB) dst[i] = lacc[i];
}

// ---------- merge replicas (atomic-free) + fused finalize/log_softmax ----------
__global__ void merge_finalize_kernel(const float4* __restrict__ partial,
                                      const float* __restrict__ bf, float* __restrict__ out) {
  int d = blockIdx.x * blockDim.x + threadIdx.x;
  if (d >= NDST) return;
  int r = d / DPB;
  int dr = d - r * DPB;
  const float4* base = partial + (size_t)r * REPL * DPB + dr;
  float a0 = 0.f, a1 = 0.f, a2 = 0.f, aw = 0.f;
#pragma unroll 4
  for (int c = 0; c < REPL; ++c) {
    float4 v = base[(size_t)c * DPB];  // lanes read consecutive float4s: coalesced
    a0 += v.x;
    a1 += v.y;
    a2 += v.z;
    aw += v.w;
  }
  float inv = 1.f / (aw + 1e-16f);
  float s0 = a0 * inv + bf[0];
  float s1 = a1 * inv + bf[1];
  float s2 = a2 * inv + bf[2];
  float mx = fmaxf(s0, fmaxf(s1, s2));
  float l = logf(__expf(s0 - mx) + __expf(s1 - mx) + __expf(s2 - mx));
  out[d * NCLS + 0] = s0 - mx - l;
  out[d * NCLS + 1] = s1 - mx - l;
  out[d * NCLS + 2] = s2 - mx - l;
}

extern "C" void kernel_launch(void* const* d_in, const int* in_sizes, int n_in,
                              void* d_out, int out_size, void* d_ws, size_t ws_size,
                              hipStream_t stream) {
  const float* x_src    = (const float*)d_in[0];
  const float* x_dst    = (const float*)d_in[1];
  const int*   edge_src = (const int*)d_in[2];
  const int*   edge_dst = (const int*)d_in[3];
  const float* W        = (const float*)d_in[4];
  const float* att_src  = (const float*)d_in[5];
  const float* att_dst  = (const float*)d_in[6];
  const float* bias     = (const float*)d_in[7];
  const float* Wc       = (const float*)d_in[8];
  const float* bc       = (const float*)d_in[9];
  float* out = (float*)d_out;

  // ---- workspace carve (256B aligned chunks) ----
  char* p = (char*)d_ws;
  auto carve = [&](size_t bytes) {
    void* r = (void*)p;
    p += (bytes + 255) & ~(size_t)255;
    return r;
  };
  float*  wa_src  = (float*)carve(FIN * 4);
  float*  wa_dst  = (float*)carve(FIN * 4);
  float*  wfc     = (float*)carve(NCLS * FIN * 4);
  float*  bf      = (float*)carve(NCLS * 4);
  float*  a_src   = (float*)carve((size_t)NSRC * 4);
  float*  a_dst   = (float*)carve((size_t)NDST * 4);
  float4* q4      = (float4*)carve((size_t)NSRC * 16);
  float*  partial = (float*)carve((size_t)RANGES * REPL * DPB * 4 * 4);  // 10.24 MB

  prep_kernel<<<FIN + 1, 64, 0, stream>>>(W, att_src, att_dst, bias, Wc, bc,
                                          wa_src, wa_dst, wfc, bf);
  {
    int rows = NSRC + NDST;
    int blocks = (rows * 32 + 255) / 256;
    matvec_fused_kernel<<<blocks, 256, 0, stream>>>(x_src, x_dst, wa_src, wa_dst, wfc,
                                                    a_src, a_dst, q4);
  }
  edge_lds_kernel<<<dim3(REPL, RANGES), TPB, 0, stream>>>(edge_src, edge_dst, a_src, a_dst,
                                                          q4, partial);
  merge_finalize_kernel<<<(NDST + 255) / 256, 256, 0, stream>>>((const float4*)partial, bf, out);
}

// Round 7
// 127.786 us; speedup vs baseline: 1.5143x; 1.0141x over previous
//
#include <hip/hip_runtime.h>
#include <float.h>

#define NSRC 100000
#define NDST 10000
#define NEDGE 320000
#define FIN 128
#define HID 256
#define NCLS 3
#define NEG_SLOPE 0.2f

#define RANGES 4                 // dst ranges (2500 dsts -> 40 KB LDS table each)
#define REPL 128                 // edge slices (replicas per range)
#define DPB (NDST / RANGES)      // 2500 dsts per range
#define EPB (NEDGE / REPL)       // 2500 edges per slice
#define TPB 1024                 // 16 waves per block; 2 blocks/CU -> 32 waves/CU

// ---------- prep (129 blocks x 64 lanes):
//   blocks 0..127: k = blockIdx -> wa_src[k], wa_dst[k], wfc[c][k] = (W@Wc)[k,c]
//   block 128: bf[c] = bias @ Wc[:,c] + bc[c]
__global__ void prep_kernel(const float* __restrict__ W, const float* __restrict__ att_src,
                            const float* __restrict__ att_dst, const float* __restrict__ bias,
                            const float* __restrict__ Wc, const float* __restrict__ bc,
                            float* __restrict__ wa_src, float* __restrict__ wa_dst,
                            float* __restrict__ wfc, float* __restrict__ bf) {
  int l = threadIdx.x;  // 0..63
  if (blockIdx.x < FIN) {
    int k = blockIdx.x;
    float4 w = ((const float4*)(W + (size_t)k * HID))[l];  // 64 lanes x 4 = 256 = HID
    int h0 = 4 * l;
    float s1 = w.x * att_src[h0] + w.y * att_src[h0 + 1] + w.z * att_src[h0 + 2] + w.w * att_src[h0 + 3];
    float s2 = w.x * att_dst[h0] + w.y * att_dst[h0 + 1] + w.z * att_dst[h0 + 2] + w.w * att_dst[h0 + 3];
    float f0 = w.x * Wc[h0 * NCLS] + w.y * Wc[(h0 + 1) * NCLS] + w.z * Wc[(h0 + 2) * NCLS] + w.w * Wc[(h0 + 3) * NCLS];
    float f1 = w.x * Wc[h0 * NCLS + 1] + w.y * Wc[(h0 + 1) * NCLS + 1] + w.z * Wc[(h0 + 2) * NCLS + 1] + w.w * Wc[(h0 + 3) * NCLS + 1];
    float f2 = w.x * Wc[h0 * NCLS + 2] + w.y * Wc[(h0 + 1) * NCLS + 2] + w.z * Wc[(h0 + 2) * NCLS + 2] + w.w * Wc[(h0 + 3) * NCLS + 2];
#pragma unroll
    for (int off = 32; off; off >>= 1) {
      s1 += __shfl_down(s1, off);
      s2 += __shfl_down(s2, off);
      f0 += __shfl_down(f0, off);
      f1 += __shfl_down(f1, off);
      f2 += __shfl_down(f2, off);
    }
    if (l == 0) {
      wa_src[k] = s1;
      wa_dst[k] = s2;
      wfc[0 * FIN + k] = f0;
      wfc[1 * FIN + k] = f1;
      wfc[2 * FIN + k] = f2;
    }
  } else {
    float b0 = 0.f, b1 = 0.f, b2 = 0.f;
#pragma unroll
    for (int j = 0; j < 4; ++j) {
      int h = l + 64 * j;
      float bi = bias[h];
      b0 += bi * Wc[h * NCLS + 0];
      b1 += bi * Wc[h * NCLS + 1];
      b2 += bi * Wc[h * NCLS + 2];
    }
#pragma unroll
    for (int off = 32; off; off >>= 1) {
      b0 += __shfl_down(b0, off);
      b1 += __shfl_down(b1, off);
      b2 += __shfl_down(b2, off);
    }
    if (l == 0) {
      bf[0] = b0 + bc[0];
      bf[1] = b1 + bc[1];
      bf[2] = b2 + bc[2];
    }
  }
}

// ---------- fused matvec over src+dst rows (half-wave per row, float4 loads)
//   row < NSRC:  a_src[row] = x.wa_src ; q4[row] = (x.Wf0, x.Wf1, x.Wf2, 1.0)
//   else (dst):  a_dst[rd]  = x.wa_dst
__global__ void matvec_fused_kernel(const float* __restrict__ x_src, const float* __restrict__ x_dst,
                                    const float* __restrict__ wa_src, const float* __restrict__ wa_dst,
                                    const float* __restrict__ wfc, float* __restrict__ a_src,
                                    float* __restrict__ a_dst, float4* __restrict__ q4) {
  int gid = blockIdx.x * blockDim.x + threadIdx.x;
  int row = gid >> 5;
  int l = threadIdx.x & 31;
  if (row < NSRC) {
    float4 v = ((const float4*)(x_src + (size_t)row * FIN))[l];
    float4 w = ((const float4*)wa_src)[l];
    float4 c0 = ((const float4*)(wfc + 0 * FIN))[l];
    float4 c1 = ((const float4*)(wfc + 1 * FIN))[l];
    float4 c2 = ((const float4*)(wfc + 2 * FIN))[l];
    float p0 = v.x * w.x + v.y * w.y + v.z * w.z + v.w * w.w;
    float p1 = v.x * c0.x + v.y * c0.y + v.z * c0.z + v.w * c0.w;
    float p2 = v.x * c1.x + v.y * c1.y + v.z * c1.z + v.w * c1.w;
    float p3 = v.x * c2.x + v.y * c2.y + v.z * c2.z + v.w * c2.w;
#pragma unroll
    for (int off = 16; off; off >>= 1) {
      p0 += __shfl_down(p0, off);
      p1 += __shfl_down(p1, off);
      p2 += __shfl_down(p2, off);
      p3 += __shfl_down(p3, off);
    }
    if (l == 0) {
      a_src[row] = p0;
      q4[row] = make_float4(p1, p2, p3, 1.0f);
    }
  } else {
    int rd = row - NSRC;
    if (rd >= NDST) return;
    float4 v = ((const float4*)(x_dst + (size_t)rd * FIN))[l];
    float4 w = ((const float4*)wa_dst)[l];
    float p = v.x * w.x + v.y * w.y + v.z * w.z + v.w * w.w;
#pragma unroll
    for (int off = 16; off; off >>= 1) p += __shfl_down(p, off);
    if (l == 0) a_dst[rd] = p;
  }
}

// ---------- edge pass, NO global atomics:
//   block (c = blockIdx.x replica, r = blockIdx.y range) scans edge slice c,
//   keeps edges with dst in range r, accumulates (w*q0,w*q1,w*q2,w) into a
//   private 40 KB LDS table via LDS atomics, then dumps to partial[r][c][.].
__global__ __launch_bounds__(TPB) void edge_lds_kernel(
    const int* __restrict__ edge_src, const int* __restrict__ edge_dst,
    const float* __restrict__ a_src, const float* __restrict__ a_dst,
    const float4* __restrict__ q4, float* __restrict__ partial) {
  __shared__ float lacc[DPB * 4];  // 40 KB
  int c = blockIdx.x;   // 0..REPL-1
  int r = blockIdx.y;   // 0..RANGES-1
  int tid = threadIdx.x;
  for (int i = tid; i < DPB * 4; i += TPB) lacc[i] = 0.f;
  __syncthreads();

  int d0 = r * DPB;
  int ebase = c * EPB;
  for (int i = tid; i < EPB; i += TPB) {
    int e = ebase + i;
    int d = edge_dst[e];
    unsigned dr = (unsigned)(d - d0);
    if (dr < (unsigned)DPB) {
      int s = edge_src[e];
      float z = a_dst[d] + a_src[s];
      float logit = (z >= 0.f) ? z : NEG_SLOPE * z;
      float w = __expf(logit);  // no max-subtraction: |logit| small for this data scale
      float4 qv = q4[s];
      float* b = lacc + dr * 4;
      atomicAdd(b + 0, w * qv.x);
      atomicAdd(b + 1, w * qv.y);
      atomicAdd(b + 2, w * qv.z);
      atomicAdd(b + 3, w);  // qv.w == 1
    }
  }
  __syncthreads();

  float* dst = partial + ((size_t)r * REPL + c) * (DPB * 4);
  for (int i = tid; i < DPB * 4; i += TPB) dst[i] = lacc[i];
}

// ---------- merge replicas (atomic-free) + fused finalize/log_softmax ----------
__global__ void merge_finalize_kernel(const float4* __restrict__ partial,
                                      const float* __restrict__ bf, float* __restrict__ out) {
  int d = blockIdx.x * blockDim.x + threadIdx.x;
  if (d >= NDST) return;
  int r = d / DPB;
  int dr = d - r * DPB;
  const float4* base = partial + (size_t)r * REPL * DPB + dr;
  float a0 = 0.f, a1 = 0.f, a2 = 0.f, aw = 0.f;
#pragma unroll 8
  for (int c = 0; c < REPL; ++c) {
    float4 v = base[(size_t)c * DPB];  // lanes read consecutive float4s: coalesced
    a0 += v.x;
    a1 += v.y;
    a2 += v.z;
    aw += v.w;
  }
  float inv = 1.f / (aw + 1e-16f);
  float s0 = a0 * inv + bf[0];
  float s1 = a1 * inv + bf[1];
  float s2 = a2 * inv + bf[2];
  float mx = fmaxf(s0, fmaxf(s1, s2));
  float l = logf(__expf(s0 - mx) + __expf(s1 - mx) + __expf(s2 - mx));
  out[d * NCLS + 0] = s0 - mx - l;
  out[d * NCLS + 1] = s1 - mx - l;
  out[d * NCLS + 2] = s2 - mx - l;
}

extern "C" void kernel_launch(void* const* d_in, const int* in_sizes, int n_in,
                              void* d_out, int out_size, void* d_ws, size_t ws_size,
                              hipStream_t stream) {
  const float* x_src    = (const float*)d_in[0];
  const float* x_dst    = (const float*)d_in[1];
  const int*   edge_src = (const int*)d_in[2];
  const int*   edge_dst = (const int*)d_in[3];
  const float* W        = (const float*)d_in[4];
  const float* att_src  = (const float*)d_in[5];
  const float* att_dst  = (const float*)d_in[6];
  const float* bias     = (const float*)d_in[7];
  const float* Wc       = (const float*)d_in[8];
  const float* bc       = (const float*)d_in[9];
  float* out = (float*)d_out;

  // ---- workspace carve (256B aligned chunks) ----
  char* p = (char*)d_ws;
  auto carve = [&](size_t bytes) {
    void* r = (void*)p;
    p += (bytes + 255) & ~(size_t)255;
    return r;
  };
  float*  wa_src  = (float*)carve(FIN * 4);
  float*  wa_dst  = (float*)carve(FIN * 4);
  float*  wfc     = (float*)carve(NCLS * FIN * 4);
  float*  bf      = (float*)carve(NCLS * 4);
  float*  a_src   = (float*)carve((size_t)NSRC * 4);
  float*  a_dst   = (float*)carve((size_t)NDST * 4);
  float4* q4      = (float4*)carve((size_t)NSRC * 16);
  float*  partial = (float*)carve((size_t)RANGES * REPL * DPB * 4 * 4);  // 20.48 MB

  prep_kernel<<<FIN + 1, 64, 0, stream>>>(W, att_src, att_dst, bias, Wc, bc,
                                          wa_src, wa_dst, wfc, bf);
  {
    int rows = NSRC + NDST;
    int blocks = (rows * 32 + 255) / 256;
    matvec_fused_kernel<<<blocks, 256, 0, stream>>>(x_src, x_dst, wa_src, wa_dst, wfc,
                                                    a_src, a_dst, q4);
  }
  edge_lds_kernel<<<dim3(REPL, RANGES), TPB, 0, stream>>>(edge_src, edge_dst, a_src, a_dst,
                                                          q4, partial);
  merge_finalize_kernel<<<(NDST + 255) / 256, 256, 0, stream>>>((const float4*)partial, bf, out);
}